// Round 7
// baseline (303.822 us; speedup 1.0000x reference)
//
#include <hip/hip_runtime.h>
#include <math.h>

// B=8, C=128, N=4096, d=16, groups=32
// attn: S^T = K @ Q^T via mfma_32x32x16_bf16 (coalesced global frags, no LDS),
//       P = exp2(S^T) (no-max softmax; Q pre-scaled by 0.25*log2e),
//       P^T B-frags via half-wave pre-select + 4x shfl_xor(32),
//       O^T = V @ P^T with V in TILED layout vt[b][j>>4][c][j&15] (coalesced).
// R6: XCD pinning (batch = blockid & 7) -> FETCH 37->5 MB (kept).
// R7: latency was the limiter (FETCH dropped 7x, time flat; VGPR=60 = nothing
//     in flight). Explicit register double-buffer of K+V frags (prefetch tile
//     t+1 during tile t), barrier-free loop -> fine-grained vmcnt overlap.
//     qkv/proj: all 64 K-loop loads hoisted up front (max MLP).

typedef short v8s __attribute__((ext_vector_type(8)));   // 8 bf16 = 4 VGPRs
typedef float v16f __attribute__((ext_vector_type(16))); // 32x32 acc

__device__ __forceinline__ unsigned short f2bf_rne(float f) {
  unsigned u = __float_as_uint(f);
  u += 0x7fffu + ((u >> 16) & 1u);
  return (unsigned short)(u >> 16);
}

__device__ __forceinline__ v8s mk8(unsigned a, unsigned b, unsigned c, unsigned d) {
  union { unsigned u[4]; v8s s; } x;
  x.u[0] = a; x.u[1] = b; x.u[2] = c; x.u[3] = d;
  return x.s;
}

// pack two fp32 -> dword of 2 bf16 (truncation) in ONE v_perm_b32
__device__ __forceinline__ unsigned pack_trunc(float hi, float lo) {
  return __builtin_amdgcn_perm(__float_as_uint(hi), __float_as_uint(lo), 0x07060302u);
}

// tiled V element index: [b][j>>4][c][j&15]
#define VT(b, n, c) (((((size_t)(b) * 256 + ((n) >> 4)) << 7) + (c)) * 16 + ((n) & 15))

// ws byte offsets
#define WSB_MURS   0u
#define WSB_WCATB  4096u       // 160*128 bf16 = 40960
#define WSB_BCAT   49152u      // 160 f32
#define WSB_PWB    65536u      // 128*128 bf16 = 32768
#define WSB_QBF    131072u     // 8*4096*16 bf16 = 1 MB
#define WSB_KBF    1310720u    // 1 MB
#define WSB_VBF    2621440u    // 8 MB (tiled)
#define WSB_ABF    11534336u   // 8 MB

// ---------------------------------------------------------------------------
__global__ void prep_kernel(const float* __restrict__ qw, const float* __restrict__ qb,
                            const float* __restrict__ kw, const float* __restrict__ kb,
                            const float* __restrict__ vw, const float* __restrict__ vb,
                            const float* __restrict__ pw,
                            unsigned short* __restrict__ wcatb, float* __restrict__ bcat,
                            unsigned short* __restrict__ pwb) {
  const float qs = 0.36067376022224085f;  // 0.25 * log2(e)
  int idx = blockIdx.x * 256 + threadIdx.x;
  if (idx < 160 * 128) {
    int o = idx >> 7, c = idx & 127;
    float val;
    if (o < 16)       val = qw[o * 128 + c] * qs;
    else if (o < 32)  val = kw[(o - 16) * 128 + c];
    else              val = vw[(o - 32) * 128 + c];
    wcatb[idx] = f2bf_rne(val);
  } else if (idx < 160 * 128 + 160) {
    int o = idx - 160 * 128;
    bcat[o] = (o < 16) ? qb[o] * qs : (o < 32) ? kb[o - 16] : vb[o - 32];
  } else if (idx < 160 * 128 + 160 + 128 * 128) {
    int j = idx - (160 * 128 + 160);
    pwb[j] = f2bf_rne(pw[j]);
  }
}

// ---------------------------------------------------------------------------
__global__ __launch_bounds__(512)
void gn_stats_kernel(const float* __restrict__ x, float* __restrict__ mu_rs) {
  const int id = blockIdx.x;              // XCD swizzle: batch = id & 7
  const int bg = (id & 7) * 32 + (id >> 3);
  const float4* xp = (const float4*)(x + (size_t)bg * 16384);
  float s = 0.f, ss = 0.f;
#pragma unroll
  for (int u = 0; u < 8; ++u) {
    int i = threadIdx.x + u * 512;
    float4 v = xp[i];
    s  += v.x + v.y + v.z + v.w;
    ss += v.x * v.x + v.y * v.y + v.z * v.z + v.w * v.w;
  }
  for (int off = 32; off > 0; off >>= 1) {
    s  += __shfl_down(s, off, 64);
    ss += __shfl_down(ss, off, 64);
  }
  __shared__ float red[16];
  int lane = threadIdx.x & 63, wid = threadIdx.x >> 6;
  if (lane == 0) { red[wid * 2] = s; red[wid * 2 + 1] = ss; }
  __syncthreads();
  if (threadIdx.x == 0) {
    float S = 0.f, SS = 0.f;
    for (int w = 0; w < 8; ++w) { S += red[w * 2]; SS += red[w * 2 + 1]; }
    float mu  = S * (1.0f / 16384.0f);
    float var = SS * (1.0f / 16384.0f) - mu * mu;
    float rs  = rsqrtf(var + 1e-5f);
    mu_rs[bg * 2]     = mu;
    mu_rs[bg * 2 + 1] = rs;
  }
}

// ---------------------------------------------------------------------------
// QKV as MFMA GEMM, GN fused. Block 512 thr (8 waves), n-tile 64.
// All 64 x-loads hoisted up front (MLP), then pack+MFMA. XCD-pinned grid.
// ---------------------------------------------------------------------------
__global__ __launch_bounds__(512)
void qkv_kernel(const float* __restrict__ x, const float* __restrict__ gnw,
                const float* __restrict__ gnb, const float* __restrict__ mu_rs,
                const unsigned short* __restrict__ wcatb, const float* __restrict__ bcat,
                unsigned short* __restrict__ qbf, unsigned short* __restrict__ kbf,
                unsigned short* __restrict__ vbf) {
  __shared__ float scs[128], shs[128], bsh[160];
  const int id = blockIdx.x;
  const int b = id & 7, nb = (id >> 3) << 6;   // XCD-pinned batch
  const int t = threadIdx.x;
  const int w = t >> 6, lane = t & 63, h = lane >> 5, l = lane & 31;
  const int nsub = w & 1, og = w >> 1;
  if (t < 128) {
    float mu = mu_rs[(b * 32 + (t >> 2)) * 2];
    float rs = mu_rs[(b * 32 + (t >> 2)) * 2 + 1];
    float gw = gnw[t], gb = gnb[t];
    scs[t] = rs * gw; shs[t] = gb - mu * rs * gw;
  }
  if (t < 160) bsh[t] = bcat[t];
  __syncthreads();

  const int n = nb + nsub * 32 + l;
  const float* xb = x + ((size_t)b * 128 << 12);
  const int otbase = (og == 0) ? 0 : og + 1; // ot index of acc[0]

  // hoist all 64 x loads (8 ks-steps x 8 channels) for max MLP
  float xv[64];
#pragma unroll
  for (int ks = 0; ks < 8; ++ks)
#pragma unroll
    for (int p = 0; p < 8; ++p)
      xv[ks * 8 + p] = xb[((size_t)(ks * 16 + 8 * h + p) << 12) + n];

  v16f acc[2];
#pragma unroll
  for (int a2 = 0; a2 < 2; ++a2)
#pragma unroll
    for (int r = 0; r < 16; ++r) acc[a2][r] = 0.f;

#pragma unroll
  for (int ks = 0; ks < 8; ++ks) {
    const int c0 = ks * 16 + 8 * h;
    unsigned fd[4];
#pragma unroll
    for (int p = 0; p < 4; ++p) {
      int ca = c0 + 2 * p;
      float h0 = xv[ks * 8 + 2 * p]     * scs[ca]     + shs[ca];
      float h1 = xv[ks * 8 + 2 * p + 1] * scs[ca + 1] + shs[ca + 1];
      fd[p] = (unsigned)f2bf_rne(h0) | ((unsigned)f2bf_rne(h1) << 16);
    }
    v8s bf = mk8(fd[0], fd[1], fd[2], fd[3]);
    {
      v8s af = *(const v8s*)(wcatb + (otbase * 32 + l) * 128 + ks * 16 + 8 * h);
      acc[0] = __builtin_amdgcn_mfma_f32_32x32x16_bf16(af, bf, acc[0], 0, 0, 0);
    }
    if (og == 0) {
      v8s af = *(const v8s*)(wcatb + (32 + l) * 128 + ks * 16 + 8 * h);
      acc[1] = __builtin_amdgcn_mfma_f32_32x32x16_bf16(af, bf, acc[1], 0, 0, 0);
    }
  }

  // epilogue
  if (og == 0) {
    const size_t nqk = ((size_t)b * 4096 + n) << 4;
#pragma unroll
    for (int r = 0; r < 16; ++r) {
      int o = 4 * h + (r & 3) + 8 * (r >> 2);
      unsigned short bv = f2bf_rne(acc[0][r] + bsh[o]);
      if (o < 16) qbf[nqk + o] = bv; else kbf[nqk + o - 16] = bv;
    }
#pragma unroll
    for (int r = 0; r < 16; ++r) {
      int o = 32 + 4 * h + (r & 3) + 8 * (r >> 2);
      vbf[VT(b, n, o - 32)] = f2bf_rne(acc[1][r] + bsh[o]);
    }
  } else {
#pragma unroll
    for (int r = 0; r < 16; ++r) {
      int o = otbase * 32 + 4 * h + (r & 3) + 8 * (r >> 2);
      vbf[VT(b, n, o - 32)] = f2bf_rne(acc[0][r] + bsh[o]);
    }
  }
}

// ---------------------------------------------------------------------------
// attn tile body, register double-buffered (CUR/NXT ping-pong).
// ---------------------------------------------------------------------------
template <int CUR, int NXT>
__device__ __forceinline__ void attn_tile(
    int tile, int h, const unsigned short* __restrict__ kl,
    const unsigned short* __restrict__ vl, const v8s& qf, const v16f& zc,
    v8s (&kb2)[2], v8s (&vb2)[2][8], v16f (&acc)[4], float& ls) {
  // prefetch tile+1 (wraps to 0 at the end — harmless re-load)
  const int tn = (tile + 1) & 31;
  kb2[NXT] = *(const v8s*)(kl + (size_t)tn * 512);
#pragma unroll
  for (int ks = 0; ks < 2; ++ks)
#pragma unroll
    for (int ct = 0; ct < 4; ++ct)
      vb2[NXT][ks * 4 + ct] =
          *(const v8s*)(vl + (size_t)tn * 4096 + ks * 2048 + ct * 512);

  // QK: S^T(32j x 32i) = K @ Q^T
  v16f st = __builtin_amdgcn_mfma_f32_32x32x16_bf16(kb2[CUR], qf, zc, 0, 0, 0);
  float p[16];
#pragma unroll
  for (int r = 0; r < 16; ++r) { p[r] = __builtin_amdgcn_exp2f(st[r]); ls += p[r]; }
  unsigned G[8];
#pragma unroll
  for (int g = 0; g < 4; ++g) {
    G[2 * g]     = pack_trunc(p[4 * g + 1], p[4 * g]);
    G[2 * g + 1] = pack_trunc(p[4 * g + 3], p[4 * g + 2]);
  }
  // half-wave exchange: pre-select what the partner half needs, 4 shfl total
  unsigned S0 = h ? G[0] : G[2], S1 = h ? G[1] : G[3];
  unsigned S2 = h ? G[4] : G[6], S3 = h ? G[5] : G[7];
  unsigned R0 = (unsigned)__shfl_xor((int)S0, 32, 64);
  unsigned R1 = (unsigned)__shfl_xor((int)S1, 32, 64);
  unsigned R2 = (unsigned)__shfl_xor((int)S2, 32, 64);
  unsigned R3 = (unsigned)__shfl_xor((int)S3, 32, 64);
  v8s pf0 = h ? mk8(R0, R1, G[2], G[3]) : mk8(G[0], G[1], R0, R1);
  v8s pf1 = h ? mk8(R2, R3, G[6], G[7]) : mk8(G[4], G[5], R2, R3);

#pragma unroll
  for (int ct = 0; ct < 4; ++ct)
    acc[ct] = __builtin_amdgcn_mfma_f32_32x32x16_bf16(vb2[CUR][ct], pf0, acc[ct], 0, 0, 0);
#pragma unroll
  for (int ct = 0; ct < 4; ++ct)
    acc[ct] = __builtin_amdgcn_mfma_f32_32x32x16_bf16(vb2[CUR][4 + ct], pf1, acc[ct], 0, 0, 0);
}

// ---------------------------------------------------------------------------
// Flash attention. Block 512 thr (8 waves). Wave w = (jc = w>>1, ihalf = w&1):
// owns j in [jc*1024, ...+1024) and one 32-i subtile. Register-pipelined
// barrier-free j-loop. Grid 512 1D, batch = id & 7 (XCD-pinned).
// ---------------------------------------------------------------------------
__global__ __launch_bounds__(512)
void attn_kernel(const unsigned short* __restrict__ qbf,
                 const unsigned short* __restrict__ kbf,
                 const unsigned short* __restrict__ vbf,
                 unsigned short* __restrict__ abf) {
  __shared__ float O_lds[128 * 64];
  __shared__ float l_lds[64];
  const int id = blockIdx.x;
  const int b = id & 7, i0 = (id >> 3) << 6;   // XCD-pinned batch
  const int t = threadIdx.x;
  const int w = t >> 6, lane = t & 63, h = lane >> 5, l = lane & 31;
  const int ihalf = w & 1, jc = w >> 1;

  for (int idx = t; idx < 128 * 64; idx += 512) O_lds[idx] = 0.f;
  if (t < 64) l_lds[t] = 0.f;
  __syncthreads();

  v16f zc;
#pragma unroll
  for (int r = 0; r < 16; ++r) zc[r] = 0.f;

  // Q B-frag: B[k=d][n=i], n=lane&31, k=8h+e -> b128 from [B,N,16]
  const v8s qf = *(const v8s*)(qbf + (((size_t)(b * 4096 + i0 + ihalf * 32 + l)) << 4) + 8 * h);

  v16f acc[4];
#pragma unroll
  for (int ct = 0; ct < 4; ++ct)
#pragma unroll
    for (int r = 0; r < 16; ++r) acc[ct][r] = 0.f;
  float ls = 0.f;

  const int jbeg = jc * 1024;
  // lane-fixed base pointers
  const unsigned short* kl =
      kbf + ((size_t)b << 16) + (((size_t)(jbeg + l)) << 4) + 8 * h;
  const unsigned short* vl =
      vbf + ((size_t)b << 19) + (((size_t)(((jbeg >> 4) << 7) + l)) << 4) + 8 * h;

  v8s kb2[2], vb2[2][8];
  kb2[0] = *(const v8s*)(kl);
#pragma unroll
  for (int ks = 0; ks < 2; ++ks)
#pragma unroll
    for (int ct = 0; ct < 4; ++ct)
      vb2[0][ks * 4 + ct] = *(const v8s*)(vl + ks * 2048 + ct * 512);

  for (int it = 0; it < 16; ++it) {
    attn_tile<0, 1>(2 * it,     h, kl, vl, qf, zc, kb2, vb2, acc, ls);
    attn_tile<1, 0>(2 * it + 1, h, kl, vl, qf, zc, kb2, vb2, acc, ls);
  }

  // combine partials across the 8 waves
  atomicAdd(&l_lds[ihalf * 32 + l], ls);
#pragma unroll
  for (int ct = 0; ct < 4; ++ct)
#pragma unroll
    for (int r = 0; r < 16; ++r) {
      int c = ct * 32 + 4 * h + (r & 3) + 8 * (r >> 2);
      atomicAdd(&O_lds[c * 64 + ihalf * 32 + l], acc[ct][r]);
    }
  __syncthreads();

  // normalize + store O^T -> abf [B,C,N] bf16
  const int i4 = (t & 15) * 4, cb = t >> 4;
  float4 l4 = *(float4*)&l_lds[i4];
  float lix = 1.f / l4.x, liy = 1.f / l4.y, liz = 1.f / l4.z, liw = 1.f / l4.w;
  for (int cc = cb; cc < 128; cc += 32) {
    float4 o4 = *(float4*)&O_lds[cc * 64 + i4];
    unsigned d0 = (unsigned)f2bf_rne(o4.x * lix) | ((unsigned)f2bf_rne(o4.y * liy) << 16);
    unsigned d1 = (unsigned)f2bf_rne(o4.z * liz) | ((unsigned)f2bf_rne(o4.w * liw) << 16);
    uint2 st2; st2.x = d0; st2.y = d1;
    *(uint2*)(abf + (((size_t)(b * 128 + cc)) << 12) + i0 + i4) = st2;
  }
}

// ---------------------------------------------------------------------------
// proj as MFMA GEMM + bias + residual. Block 512 thr (8 waves), n-tile 64:
// nsub = w&1, ot = w>>1. All 64 abf loads hoisted up front. XCD-pinned grid.
// ---------------------------------------------------------------------------
__global__ __launch_bounds__(512)
void proj_kernel(const unsigned short* __restrict__ abf, const unsigned short* __restrict__ pwb,
                 const float* __restrict__ pb, const float* __restrict__ x,
                 float* __restrict__ out) {
  __shared__ float pbs[128];
  const int id = blockIdx.x;
  const int b = id & 7, nb = (id >> 3) << 6;   // XCD-pinned batch
  const int t = threadIdx.x;
  const int w = t >> 6, lane = t & 63, h = lane >> 5, l = lane & 31;
  const int nsub = w & 1, ot = w >> 1;
  if (t < 128) pbs[t] = pb[t];
  __syncthreads();

  const int n = nb + nsub * 32 + l;
  const unsigned short* ab = abf + (((size_t)b * 128) << 12);

  // hoist all 64 abf loads
  unsigned short av[64];
#pragma unroll
  for (int ks = 0; ks < 8; ++ks)
#pragma unroll
    for (int p = 0; p < 8; ++p)
      av[ks * 8 + p] = ab[((size_t)(ks * 16 + 8 * h + p) << 12) + n];

  v16f acc;
#pragma unroll
  for (int r = 0; r < 16; ++r) acc[r] = 0.f;

#pragma unroll
  for (int ks = 0; ks < 8; ++ks) {
    unsigned fd[4];
#pragma unroll
    for (int p = 0; p < 4; ++p)
      fd[p] = (unsigned)av[ks * 8 + 2 * p] | ((unsigned)av[ks * 8 + 2 * p + 1] << 16);
    v8s bf = mk8(fd[0], fd[1], fd[2], fd[3]);
    v8s af = *(const v8s*)(pwb + (ot * 32 + l) * 128 + ks * 16 + 8 * h);
    acc = __builtin_amdgcn_mfma_f32_32x32x16_bf16(af, bf, acc, 0, 0, 0);
  }

#pragma unroll
  for (int r = 0; r < 16; ++r) {
    int e = ot * 32 + 4 * h + (r & 3) + 8 * (r >> 2);
    size_t idx = ((size_t)(b * 128 + e) << 12) + n;
    out[idx] = acc[r] + pbs[e] + x[idx];
  }
}

// ---------------------------------------------------------------------------
extern "C" void kernel_launch(void* const* d_in, const int* in_sizes, int n_in,
                              void* d_out, int out_size, void* d_ws, size_t ws_size,
                              hipStream_t stream) {
  const float* x   = (const float*)d_in[0];
  const float* gnw = (const float*)d_in[1];
  const float* gnb = (const float*)d_in[2];
  const float* qw  = (const float*)d_in[3];
  const float* qb  = (const float*)d_in[4];
  const float* kw  = (const float*)d_in[5];
  const float* kb  = (const float*)d_in[6];
  const float* vw  = (const float*)d_in[7];
  const float* vb  = (const float*)d_in[8];
  const float* pw  = (const float*)d_in[9];
  const float* pb  = (const float*)d_in[10];
  float* out = (float*)d_out;
  char* ws = (char*)d_ws;

  float* mu_rs = (float*)(ws + WSB_MURS);
  unsigned short* wcatb = (unsigned short*)(ws + WSB_WCATB);
  float* bcat = (float*)(ws + WSB_BCAT);
  unsigned short* pwb = (unsigned short*)(ws + WSB_PWB);
  unsigned short* qbf = (unsigned short*)(ws + WSB_QBF);
  unsigned short* kbf = (unsigned short*)(ws + WSB_KBF);
  unsigned short* vbf = (unsigned short*)(ws + WSB_VBF);
  unsigned short* abf = (unsigned short*)(ws + WSB_ABF);

  hipLaunchKernelGGL(prep_kernel, dim3(145), dim3(256), 0, stream,
                     qw, qb, kw, kb, vw, vb, pw, wcatb, bcat, pwb);
  hipLaunchKernelGGL(gn_stats_kernel, dim3(256), dim3(512), 0, stream, x, mu_rs);
  hipLaunchKernelGGL(qkv_kernel, dim3(512), dim3(512), 0, stream,
                     x, gnw, gnb, mu_rs, wcatb, bcat, qbf, kbf, vbf);
  hipLaunchKernelGGL(attn_kernel, dim3(512), dim3(512), 0, stream,
                     qbf, kbf, vbf, abf);
  hipLaunchKernelGGL(proj_kernel, dim3(512), dim3(512), 0, stream,
                     abf, pwb, pb, x, out);
}

// Round 10
// 177.681 us; speedup vs baseline: 1.7099x; 1.7099x over previous
//
#include <hip/hip_runtime.h>
#include <math.h>

// B=8, C=128, N=4096, d=16, groups=32
// R10 attn: LDS-staged flash attention, hazard-free (3 barriers/tile).
//   Block = (batch b, 128-i tile), 512 thr, grid 256 (1 blk/CU, XCD-pinned).
//   Per 64-j tile:
//     A: V(16KB)+K(2KB) global->regs   [R9 BUG FIX: use full lane index --
//        (l>>1) with l=lane&31 left half of every 32-row group unstaged ->
//        LDS garbage -> NaN in both R8 and R9]
//     barrier; ds_write KV (rows padded to 40 shorts = 80B: b128 reads tile
//        all 32 banks conflict-free per 8-lane phase); barrier
//     QK (wave = jsub x iquad 32x32 patch) -> exp2 -> P bf16 to LDS s72
//     barrier; PV (wave = ct x ipair), full-K per wave -> acc FINAL
//   Epilogue: l via LDS atomics; direct normalized stores.

typedef short v8s __attribute__((ext_vector_type(8)));   // 8 bf16 = 4 VGPRs
typedef float v16f __attribute__((ext_vector_type(16))); // 32x32 acc

__device__ __forceinline__ unsigned short f2bf_rne(float f) {
  unsigned u = __float_as_uint(f);
  u += 0x7fffu + ((u >> 16) & 1u);
  return (unsigned short)(u >> 16);
}

__device__ __forceinline__ v8s mk8(unsigned a, unsigned b, unsigned c, unsigned d) {
  union { unsigned u[4]; v8s s; } x;
  x.u[0] = a; x.u[1] = b; x.u[2] = c; x.u[3] = d;
  return x.s;
}

// pack two fp32 -> dword of 2 bf16 (truncation) in ONE v_perm_b32
__device__ __forceinline__ unsigned pack_trunc(float hi, float lo) {
  return __builtin_amdgcn_perm(__float_as_uint(hi), __float_as_uint(lo), 0x07060302u);
}

// tiled V element index: [b][j>>4][c][j&15]
#define VT(b, n, c) (((((size_t)(b) * 256 + ((n) >> 4)) << 7) + (c)) * 16 + ((n) & 15))

// ws byte offsets
#define WSB_MURS   0u
#define WSB_WCATB  4096u       // 160*128 bf16 = 40960
#define WSB_BCAT   49152u      // 160 f32
#define WSB_PWB    65536u      // 128*128 bf16 = 32768
#define WSB_QBF    131072u     // 8*4096*16 bf16 = 1 MB
#define WSB_KBF    1310720u    // 1 MB
#define WSB_VBF    2621440u    // 8 MB (tiled)
#define WSB_ABF    11534336u   // 8 MB

// ---------------------------------------------------------------------------
__global__ void prep_kernel(const float* __restrict__ qw, const float* __restrict__ qb,
                            const float* __restrict__ kw, const float* __restrict__ kb,
                            const float* __restrict__ vw, const float* __restrict__ vb,
                            const float* __restrict__ pw,
                            unsigned short* __restrict__ wcatb, float* __restrict__ bcat,
                            unsigned short* __restrict__ pwb) {
  const float qs = 0.36067376022224085f;  // 0.25 * log2(e)
  int idx = blockIdx.x * 256 + threadIdx.x;
  if (idx < 160 * 128) {
    int o = idx >> 7, c = idx & 127;
    float val;
    if (o < 16)       val = qw[o * 128 + c] * qs;
    else if (o < 32)  val = kw[(o - 16) * 128 + c];
    else              val = vw[(o - 32) * 128 + c];
    wcatb[idx] = f2bf_rne(val);
  } else if (idx < 160 * 128 + 160) {
    int o = idx - 160 * 128;
    bcat[o] = (o < 16) ? qb[o] * qs : (o < 32) ? kb[o - 16] : vb[o - 32];
  } else if (idx < 160 * 128 + 160 + 128 * 128) {
    int j = idx - (160 * 128 + 160);
    pwb[j] = f2bf_rne(pw[j]);
  }
}

// ---------------------------------------------------------------------------
__global__ __launch_bounds__(512)
void gn_stats_kernel(const float* __restrict__ x, float* __restrict__ mu_rs) {
  const int id = blockIdx.x;              // XCD swizzle: batch = id & 7
  const int bg = (id & 7) * 32 + (id >> 3);
  const float4* xp = (const float4*)(x + (size_t)bg * 16384);
  float s = 0.f, ss = 0.f;
#pragma unroll
  for (int u = 0; u < 8; ++u) {
    int i = threadIdx.x + u * 512;
    float4 v = xp[i];
    s  += v.x + v.y + v.z + v.w;
    ss += v.x * v.x + v.y * v.y + v.z * v.z + v.w * v.w;
  }
  for (int off = 32; off > 0; off >>= 1) {
    s  += __shfl_down(s, off, 64);
    ss += __shfl_down(ss, off, 64);
  }
  __shared__ float red[16];
  int lane = threadIdx.x & 63, wid = threadIdx.x >> 6;
  if (lane == 0) { red[wid * 2] = s; red[wid * 2 + 1] = ss; }
  __syncthreads();
  if (threadIdx.x == 0) {
    float S = 0.f, SS = 0.f;
    for (int w = 0; w < 8; ++w) { S += red[w * 2]; SS += red[w * 2 + 1]; }
    float mu  = S * (1.0f / 16384.0f);
    float var = SS * (1.0f / 16384.0f) - mu * mu;
    float rs  = rsqrtf(var + 1e-5f);
    mu_rs[bg * 2]     = mu;
    mu_rs[bg * 2 + 1] = rs;
  }
}

// ---------------------------------------------------------------------------
// QKV as MFMA GEMM, GN fused. Block 512 thr (8 waves), n-tile 64.
// All 64 x-loads hoisted up front (MLP), then pack+MFMA. XCD-pinned grid.
// ---------------------------------------------------------------------------
__global__ __launch_bounds__(512)
void qkv_kernel(const float* __restrict__ x, const float* __restrict__ gnw,
                const float* __restrict__ gnb, const float* __restrict__ mu_rs,
                const unsigned short* __restrict__ wcatb, const float* __restrict__ bcat,
                unsigned short* __restrict__ qbf, unsigned short* __restrict__ kbf,
                unsigned short* __restrict__ vbf) {
  __shared__ float scs[128], shs[128], bsh[160];
  const int id = blockIdx.x;
  const int b = id & 7, nb = (id >> 3) << 6;   // XCD-pinned batch
  const int t = threadIdx.x;
  const int w = t >> 6, lane = t & 63, h = lane >> 5, l = lane & 31;
  const int nsub = w & 1, og = w >> 1;
  if (t < 128) {
    float mu = mu_rs[(b * 32 + (t >> 2)) * 2];
    float rs = mu_rs[(b * 32 + (t >> 2)) * 2 + 1];
    float gw = gnw[t], gb = gnb[t];
    scs[t] = rs * gw; shs[t] = gb - mu * rs * gw;
  }
  if (t < 160) bsh[t] = bcat[t];
  __syncthreads();

  const int n = nb + nsub * 32 + l;
  const float* xb = x + ((size_t)b * 128 << 12);
  const int otbase = (og == 0) ? 0 : og + 1; // ot index of acc[0]

  // hoist all 64 x loads (8 ks-steps x 8 channels) for max MLP
  float xv[64];
#pragma unroll
  for (int ks = 0; ks < 8; ++ks)
#pragma unroll
    for (int p = 0; p < 8; ++p)
      xv[ks * 8 + p] = xb[((size_t)(ks * 16 + 8 * h + p) << 12) + n];

  v16f acc[2];
#pragma unroll
  for (int a2 = 0; a2 < 2; ++a2)
#pragma unroll
    for (int r = 0; r < 16; ++r) acc[a2][r] = 0.f;

#pragma unroll
  for (int ks = 0; ks < 8; ++ks) {
    const int c0 = ks * 16 + 8 * h;
    unsigned fd[4];
#pragma unroll
    for (int p = 0; p < 4; ++p) {
      int ca = c0 + 2 * p;
      float h0 = xv[ks * 8 + 2 * p]     * scs[ca]     + shs[ca];
      float h1 = xv[ks * 8 + 2 * p + 1] * scs[ca + 1] + shs[ca + 1];
      fd[p] = (unsigned)f2bf_rne(h0) | ((unsigned)f2bf_rne(h1) << 16);
    }
    v8s bf = mk8(fd[0], fd[1], fd[2], fd[3]);
    {
      v8s af = *(const v8s*)(wcatb + (otbase * 32 + l) * 128 + ks * 16 + 8 * h);
      acc[0] = __builtin_amdgcn_mfma_f32_32x32x16_bf16(af, bf, acc[0], 0, 0, 0);
    }
    if (og == 0) {
      v8s af = *(const v8s*)(wcatb + (32 + l) * 128 + ks * 16 + 8 * h);
      acc[1] = __builtin_amdgcn_mfma_f32_32x32x16_bf16(af, bf, acc[1], 0, 0, 0);
    }
  }

  // epilogue
  if (og == 0) {
    const size_t nqk = ((size_t)b * 4096 + n) << 4;
#pragma unroll
    for (int r = 0; r < 16; ++r) {
      int o = 4 * h + (r & 3) + 8 * (r >> 2);
      unsigned short bv = f2bf_rne(acc[0][r] + bsh[o]);
      if (o < 16) qbf[nqk + o] = bv; else kbf[nqk + o - 16] = bv;
    }
#pragma unroll
    for (int r = 0; r < 16; ++r) {
      int o = 32 + 4 * h + (r & 3) + 8 * (r >> 2);
      vbf[VT(b, n, o - 32)] = f2bf_rne(acc[1][r] + bsh[o]);
    }
  } else {
#pragma unroll
    for (int r = 0; r < 16; ++r) {
      int o = otbase * 32 + 4 * h + (r & 3) + 8 * (r >> 2);
      vbf[VT(b, n, o - 32)] = f2bf_rne(acc[0][r] + bsh[o]);
    }
  }
}

// ---------------------------------------------------------------------------
// R10 flash attention, LDS-staged, hazard-free. Block 512 thr (8 waves) =
// (batch, 128-i tile). Grid 256, XCD-pinned (b = id & 7).
// KV rows padded to 40 shorts (80 B) for conflict-free b128 reads.
// ---------------------------------------------------------------------------
#define VS 40                     // shorts per KV row (16 data + 24 pad)
#define KOFF (512 * VS)           // K region start (shorts)

__global__ __launch_bounds__(512)
void attn_kernel(const unsigned short* __restrict__ qbf,
                 const unsigned short* __restrict__ kbf,
                 const unsigned short* __restrict__ vbf,
                 unsigned short* __restrict__ abf) {
  __shared__ alignas(16) unsigned short kvs[KOFF + 64 * VS];  // 46.1 KB
  __shared__ alignas(16) unsigned short pbuf[128 * 72];       // 18.4 KB
  __shared__ float l_lds[128];

  const int id = blockIdx.x;
  const int b = id & 7, i0 = (id >> 3) << 7;   // XCD-pinned batch, 128-i tile
  const int t = threadIdx.x;
  const int w = t >> 6, lane = t & 63, h = lane >> 5, l = lane & 31;
  const int jsub = w & 1, iquad = w >> 1;      // QK role
  const int ipair = w & 1, ct = w >> 1;        // PV role (full-K per wave)

  const unsigned short* kg = kbf + ((size_t)b << 16);
  const unsigned short* vg = vbf + ((size_t)b << 19);

  // Q B-frag for this wave's iquad (held in regs all kernel)
  const v8s qf = *(const v8s*)(qbf + (((size_t)(b * 4096 + i0 + iquad * 32 + l)) << 4) + 8 * h);

  v16f zc;
#pragma unroll
  for (int r = 0; r < 16; ++r) zc[r] = 0.f;
  v16f acc0, acc1;
#pragma unroll
  for (int r = 0; r < 16; ++r) { acc0[r] = 0.f; acc1[r] = 0.f; }
  float ls = 0.f;

  // staging geometry (FULL 64-lane index — R9 bug was using lane&31):
  // V tile = 512 rows x 16 shorts; wave w stages rows [w*64, w*64+64);
  // lane covers (row = base + (lane>>1), 16B half = lane&1).
  const int vrow = w * 64 + (lane >> 1);
  const int sh16 = (lane & 1) * 8;
  const int krow = (w & 1) * 32 + (lane >> 1);

  if (t < 128) l_lds[t] = 0.f;

  for (int tile = 0; tile < 64; ++tile) {
    // A: global loads into regs (coalesced 2KB per wave-load)
    v8s s0 = *(const v8s*)(vg + (size_t)tile * 8192 + vrow * 16 + sh16);
    v8s s1 = *(const v8s*)(vg + (size_t)tile * 8192 + (vrow + 32) * 16 + sh16);
    v8s sk = {};
    if (w < 2) sk = *(const v8s*)(kg + (size_t)tile * 1024 + krow * 16 + sh16);

    __syncthreads();   // previous PV done reading kvs/pbuf (also l_lds init)

    *(v8s*)(kvs + vrow * VS + sh16) = s0;
    *(v8s*)(kvs + (vrow + 32) * VS + sh16) = s1;
    if (w < 2) *(v8s*)(kvs + KOFF + krow * VS + sh16) = sk;

    __syncthreads();   // KV staged

    // QK for this wave's (jsub, iquad) 32x32 patch
    v8s kf = *(const v8s*)(kvs + KOFF + (jsub * 32 + l) * VS + 8 * h);
    v16f st = __builtin_amdgcn_mfma_f32_32x32x16_bf16(kf, qf, zc, 0, 0, 0);
    float pe[16];
#pragma unroll
    for (int r = 0; r < 16; ++r) { pe[r] = __builtin_amdgcn_exp2f(st[r]); ls += pe[r]; }
    {
      unsigned* prow = (unsigned*)(pbuf + (iquad * 32 + l) * 72);
#pragma unroll
      for (int q = 0; q < 4; ++q) {
        const int jq = jsub * 32 + 4 * h + 8 * q;   // even
        prow[(jq >> 1)]     = pack_trunc(pe[4 * q + 1], pe[4 * q]);
        prow[(jq >> 1) + 1] = pack_trunc(pe[4 * q + 3], pe[4 * q + 2]);
      }
    }

    __syncthreads();   // P ready (KV still valid)

    // PV for this wave's (ct, ipair): full K (4 ksteps), acc is FINAL
#pragma unroll
    for (int ks = 0; ks < 4; ++ks) {
      v8s vf  = *(const v8s*)(kvs + (ks * 128 + ct * 32 + l) * VS + 8 * h);
      v8s pfa = *(const v8s*)(pbuf + ((ipair * 2)     * 32 + l) * 72 + ks * 16 + 8 * h);
      v8s pfb = *(const v8s*)(pbuf + ((ipair * 2 + 1) * 32 + l) * 72 + ks * 16 + 8 * h);
      acc0 = __builtin_amdgcn_mfma_f32_32x32x16_bf16(vf, pfa, acc0, 0, 0, 0);
      acc1 = __builtin_amdgcn_mfma_f32_32x32x16_bf16(vf, pfb, acc1, 0, 0, 0);
    }
  }

  // epilogue: l combine (2 jsub waves + 2 h halves per i), then normalize+store
  atomicAdd(&l_lds[iquad * 32 + l], ls);
  __syncthreads();
  const float li0 = 1.f / l_lds[ipair * 64 + l];
  const float li1 = 1.f / l_lds[ipair * 64 + 32 + l];
#pragma unroll
  for (int r = 0; r < 16; ++r) {
    int c = ct * 32 + 4 * h + (r & 3) + 8 * (r >> 2);
    size_t base = ((size_t)(b * 128 + c) << 12) + i0 + ipair * 64 + l;
    abf[base]      = f2bf_rne(acc0[r] * li0);
    abf[base + 32] = f2bf_rne(acc1[r] * li1);
  }
}

// ---------------------------------------------------------------------------
// proj as MFMA GEMM + bias + residual. Block 512 thr (8 waves), n-tile 64:
// nsub = w&1, ot = w>>1. All 64 abf loads hoisted up front. XCD-pinned grid.
// ---------------------------------------------------------------------------
__global__ __launch_bounds__(512)
void proj_kernel(const unsigned short* __restrict__ abf, const unsigned short* __restrict__ pwb,
                 const float* __restrict__ pb, const float* __restrict__ x,
                 float* __restrict__ out) {
  __shared__ float pbs[128];
  const int id = blockIdx.x;
  const int b = id & 7, nb = (id >> 3) << 6;   // XCD-pinned batch
  const int t = threadIdx.x;
  const int w = t >> 6, lane = t & 63, h = lane >> 5, l = lane & 31;
  const int nsub = w & 1, ot = w >> 1;
  if (t < 128) pbs[t] = pb[t];
  __syncthreads();

  const int n = nb + nsub * 32 + l;
  const unsigned short* ab = abf + (((size_t)b * 128) << 12);

  // hoist all 64 abf loads
  unsigned short av[64];
#pragma unroll
  for (int ks = 0; ks < 8; ++ks)
#pragma unroll
    for (int p = 0; p < 8; ++p)
      av[ks * 8 + p] = ab[((size_t)(ks * 16 + 8 * h + p) << 12) + n];

  v16f acc;
#pragma unroll
  for (int r = 0; r < 16; ++r) acc[r] = 0.f;

#pragma unroll
  for (int ks = 0; ks < 8; ++ks) {
    unsigned fd[4];
#pragma unroll
    for (int p = 0; p < 4; ++p)
      fd[p] = (unsigned)av[ks * 8 + 2 * p] | ((unsigned)av[ks * 8 + 2 * p + 1] << 16);
    v8s bf = mk8(fd[0], fd[1], fd[2], fd[3]);
    v8s af = *(const v8s*)(pwb + (ot * 32 + l) * 128 + ks * 16 + 8 * h);
    acc = __builtin_amdgcn_mfma_f32_32x32x16_bf16(af, bf, acc, 0, 0, 0);
  }

#pragma unroll
  for (int r = 0; r < 16; ++r) {
    int e = ot * 32 + 4 * h + (r & 3) + 8 * (r >> 2);
    size_t idx = ((size_t)(b * 128 + e) << 12) + n;
    out[idx] = acc[r] + pbs[e] + x[idx];
  }
}

// ---------------------------------------------------------------------------
extern "C" void kernel_launch(void* const* d_in, const int* in_sizes, int n_in,
                              void* d_out, int out_size, void* d_ws, size_t ws_size,
                              hipStream_t stream) {
  const float* x   = (const float*)d_in[0];
  const float* gnw = (const float*)d_in[1];
  const float* gnb = (const float*)d_in[2];
  const float* qw  = (const float*)d_in[3];
  const float* qb  = (const float*)d_in[4];
  const float* kw  = (const float*)d_in[5];
  const float* kb  = (const float*)d_in[6];
  const float* vw  = (const float*)d_in[7];
  const float* vb  = (const float*)d_in[8];
  const float* pw  = (const float*)d_in[9];
  const float* pb  = (const float*)d_in[10];
  float* out = (float*)d_out;
  char* ws = (char*)d_ws;

  float* mu_rs = (float*)(ws + WSB_MURS);
  unsigned short* wcatb = (unsigned short*)(ws + WSB_WCATB);
  float* bcat = (float*)(ws + WSB_BCAT);
  unsigned short* pwb = (unsigned short*)(ws + WSB_PWB);
  unsigned short* qbf = (unsigned short*)(ws + WSB_QBF);
  unsigned short* kbf = (unsigned short*)(ws + WSB_KBF);
  unsigned short* vbf = (unsigned short*)(ws + WSB_VBF);
  unsigned short* abf = (unsigned short*)(ws + WSB_ABF);

  hipLaunchKernelGGL(prep_kernel, dim3(145), dim3(256), 0, stream,
                     qw, qb, kw, kb, vw, vb, pw, wcatb, bcat, pwb);
  hipLaunchKernelGGL(gn_stats_kernel, dim3(256), dim3(512), 0, stream, x, mu_rs);
  hipLaunchKernelGGL(qkv_kernel, dim3(512), dim3(512), 0, stream,
                     x, gnw, gnb, mu_rs, wcatb, bcat, qbf, kbf, vbf);
  hipLaunchKernelGGL(attn_kernel, dim3(256), dim3(512), 0, stream,
                     qbf, kbf, vbf, abf);
  hipLaunchKernelGGL(proj_kernel, dim3(512), dim3(512), 0, stream,
                     abf, pwb, pb, x, out);
}

// Round 11
// 170.988 us; speedup vs baseline: 1.7769x; 1.0391x over previous
//
#include <hip/hip_runtime.h>
#include <math.h>

// B=8, C=128, N=4096, d=16, groups=32
// R11 attn: LDS-staged V + register-resident P.
//   Block = (batch b, 128-i tile), 512 thr, grid 256, XCD-pinned (b = id&7).
//   Wave = (jsub = w&1, iquad = w>>1): computes its own 32x32 S^T patch
//   (K A-frag DIRECT from global, Q B-frag in regs), exp2 -> P packed in
//   regs, converted to PV B-frags via proven half-wave preselect + 4x
//   shfl_xor(32) (R5/R7 mapping), then PV over all 4 ct from LDS V:
//   8 vf b128 reads + 8 MFMAs -> acc[4] (final for its jsub half).
//   End: jsub=1 waves write acc to 64KB LDS overlay (V buffer dead),
//   jsub=0 adds, normalizes by l (LDS atomics), stores.
// R10 post-mortem: LDS pipe was ~70% of wall (186 DS instr/tile/CU incl.
//   64 conflicted P b32 writes). R11 cuts to ~112 instr and 0 P traffic.

typedef short v8s __attribute__((ext_vector_type(8)));   // 8 bf16 = 4 VGPRs
typedef float v16f __attribute__((ext_vector_type(16))); // 32x32 acc

__device__ __forceinline__ unsigned short f2bf_rne(float f) {
  unsigned u = __float_as_uint(f);
  u += 0x7fffu + ((u >> 16) & 1u);
  return (unsigned short)(u >> 16);
}

__device__ __forceinline__ v8s mk8(unsigned a, unsigned b, unsigned c, unsigned d) {
  union { unsigned u[4]; v8s s; } x;
  x.u[0] = a; x.u[1] = b; x.u[2] = c; x.u[3] = d;
  return x.s;
}

// pack two fp32 -> dword of 2 bf16 (truncation) in ONE v_perm_b32
__device__ __forceinline__ unsigned pack_trunc(float hi, float lo) {
  return __builtin_amdgcn_perm(__float_as_uint(hi), __float_as_uint(lo), 0x07060302u);
}

// tiled V element index: [b][j>>4][c][j&15]
#define VT(b, n, c) (((((size_t)(b) * 256 + ((n) >> 4)) << 7) + (c)) * 16 + ((n) & 15))

// ws byte offsets
#define WSB_MURS   0u
#define WSB_WCATB  4096u       // 160*128 bf16 = 40960
#define WSB_BCAT   49152u      // 160 f32
#define WSB_PWB    65536u      // 128*128 bf16 = 32768
#define WSB_QBF    131072u     // 8*4096*16 bf16 = 1 MB
#define WSB_KBF    1310720u    // 1 MB
#define WSB_VBF    2621440u    // 8 MB (tiled)
#define WSB_ABF    11534336u   // 8 MB

// ---------------------------------------------------------------------------
__global__ void prep_kernel(const float* __restrict__ qw, const float* __restrict__ qb,
                            const float* __restrict__ kw, const float* __restrict__ kb,
                            const float* __restrict__ vw, const float* __restrict__ vb,
                            const float* __restrict__ pw,
                            unsigned short* __restrict__ wcatb, float* __restrict__ bcat,
                            unsigned short* __restrict__ pwb) {
  const float qs = 0.36067376022224085f;  // 0.25 * log2(e)
  int idx = blockIdx.x * 256 + threadIdx.x;
  if (idx < 160 * 128) {
    int o = idx >> 7, c = idx & 127;
    float val;
    if (o < 16)       val = qw[o * 128 + c] * qs;
    else if (o < 32)  val = kw[(o - 16) * 128 + c];
    else              val = vw[(o - 32) * 128 + c];
    wcatb[idx] = f2bf_rne(val);
  } else if (idx < 160 * 128 + 160) {
    int o = idx - 160 * 128;
    bcat[o] = (o < 16) ? qb[o] * qs : (o < 32) ? kb[o - 16] : vb[o - 32];
  } else if (idx < 160 * 128 + 160 + 128 * 128) {
    int j = idx - (160 * 128 + 160);
    pwb[j] = f2bf_rne(pw[j]);
  }
}

// ---------------------------------------------------------------------------
__global__ __launch_bounds__(512)
void gn_stats_kernel(const float* __restrict__ x, float* __restrict__ mu_rs) {
  const int id = blockIdx.x;              // XCD swizzle: batch = id & 7
  const int bg = (id & 7) * 32 + (id >> 3);
  const float4* xp = (const float4*)(x + (size_t)bg * 16384);
  float s = 0.f, ss = 0.f;
#pragma unroll
  for (int u = 0; u < 8; ++u) {
    int i = threadIdx.x + u * 512;
    float4 v = xp[i];
    s  += v.x + v.y + v.z + v.w;
    ss += v.x * v.x + v.y * v.y + v.z * v.z + v.w * v.w;
  }
  for (int off = 32; off > 0; off >>= 1) {
    s  += __shfl_down(s, off, 64);
    ss += __shfl_down(ss, off, 64);
  }
  __shared__ float red[16];
  int lane = threadIdx.x & 63, wid = threadIdx.x >> 6;
  if (lane == 0) { red[wid * 2] = s; red[wid * 2 + 1] = ss; }
  __syncthreads();
  if (threadIdx.x == 0) {
    float S = 0.f, SS = 0.f;
    for (int w = 0; w < 8; ++w) { S += red[w * 2]; SS += red[w * 2 + 1]; }
    float mu  = S * (1.0f / 16384.0f);
    float var = SS * (1.0f / 16384.0f) - mu * mu;
    float rs  = rsqrtf(var + 1e-5f);
    mu_rs[bg * 2]     = mu;
    mu_rs[bg * 2 + 1] = rs;
  }
}

// ---------------------------------------------------------------------------
// QKV as MFMA GEMM, GN fused. Block 512 thr (8 waves), n-tile 64.
// All 64 x-loads hoisted up front (MLP), then pack+MFMA. XCD-pinned grid.
// ---------------------------------------------------------------------------
__global__ __launch_bounds__(512)
void qkv_kernel(const float* __restrict__ x, const float* __restrict__ gnw,
                const float* __restrict__ gnb, const float* __restrict__ mu_rs,
                const unsigned short* __restrict__ wcatb, const float* __restrict__ bcat,
                unsigned short* __restrict__ qbf, unsigned short* __restrict__ kbf,
                unsigned short* __restrict__ vbf) {
  __shared__ float scs[128], shs[128], bsh[160];
  const int id = blockIdx.x;
  const int b = id & 7, nb = (id >> 3) << 6;   // XCD-pinned batch
  const int t = threadIdx.x;
  const int w = t >> 6, lane = t & 63, h = lane >> 5, l = lane & 31;
  const int nsub = w & 1, og = w >> 1;
  if (t < 128) {
    float mu = mu_rs[(b * 32 + (t >> 2)) * 2];
    float rs = mu_rs[(b * 32 + (t >> 2)) * 2 + 1];
    float gw = gnw[t], gb = gnb[t];
    scs[t] = rs * gw; shs[t] = gb - mu * rs * gw;
  }
  if (t < 160) bsh[t] = bcat[t];
  __syncthreads();

  const int n = nb + nsub * 32 + l;
  const float* xb = x + ((size_t)b * 128 << 12);
  const int otbase = (og == 0) ? 0 : og + 1; // ot index of acc[0]

  // hoist all 64 x loads (8 ks-steps x 8 channels) for max MLP
  float xv[64];
#pragma unroll
  for (int ks = 0; ks < 8; ++ks)
#pragma unroll
    for (int p = 0; p < 8; ++p)
      xv[ks * 8 + p] = xb[((size_t)(ks * 16 + 8 * h + p) << 12) + n];

  v16f acc[2];
#pragma unroll
  for (int a2 = 0; a2 < 2; ++a2)
#pragma unroll
    for (int r = 0; r < 16; ++r) acc[a2][r] = 0.f;

#pragma unroll
  for (int ks = 0; ks < 8; ++ks) {
    const int c0 = ks * 16 + 8 * h;
    unsigned fd[4];
#pragma unroll
    for (int p = 0; p < 4; ++p) {
      int ca = c0 + 2 * p;
      float h0 = xv[ks * 8 + 2 * p]     * scs[ca]     + shs[ca];
      float h1 = xv[ks * 8 + 2 * p + 1] * scs[ca + 1] + shs[ca + 1];
      fd[p] = (unsigned)f2bf_rne(h0) | ((unsigned)f2bf_rne(h1) << 16);
    }
    v8s bf = mk8(fd[0], fd[1], fd[2], fd[3]);
    {
      v8s af = *(const v8s*)(wcatb + (otbase * 32 + l) * 128 + ks * 16 + 8 * h);
      acc[0] = __builtin_amdgcn_mfma_f32_32x32x16_bf16(af, bf, acc[0], 0, 0, 0);
    }
    if (og == 0) {
      v8s af = *(const v8s*)(wcatb + (32 + l) * 128 + ks * 16 + 8 * h);
      acc[1] = __builtin_amdgcn_mfma_f32_32x32x16_bf16(af, bf, acc[1], 0, 0, 0);
    }
  }

  // epilogue
  if (og == 0) {
    const size_t nqk = ((size_t)b * 4096 + n) << 4;
#pragma unroll
    for (int r = 0; r < 16; ++r) {
      int o = 4 * h + (r & 3) + 8 * (r >> 2);
      unsigned short bv = f2bf_rne(acc[0][r] + bsh[o]);
      if (o < 16) qbf[nqk + o] = bv; else kbf[nqk + o - 16] = bv;
    }
#pragma unroll
    for (int r = 0; r < 16; ++r) {
      int o = 32 + 4 * h + (r & 3) + 8 * (r >> 2);
      vbf[VT(b, n, o - 32)] = f2bf_rne(acc[1][r] + bsh[o]);
    }
  } else {
#pragma unroll
    for (int r = 0; r < 16; ++r) {
      int o = otbase * 32 + 4 * h + (r & 3) + 8 * (r >> 2);
      vbf[VT(b, n, o - 32)] = f2bf_rne(acc[0][r] + bsh[o]);
    }
  }
}

// ---------------------------------------------------------------------------
// R11 flash attention. V LDS-staged (rows padded to 40 shorts = conflict-free
// b128), K direct global, P in registers. 2 barriers/tile.
// ---------------------------------------------------------------------------
#define VS 40                     // shorts per V row (16 data + 24 pad)

__global__ __launch_bounds__(512)
void attn_kernel(const unsigned short* __restrict__ qbf,
                 const unsigned short* __restrict__ kbf,
                 const unsigned short* __restrict__ vbf,
                 unsigned short* __restrict__ abf) {
  // overlay: V buffer (512*VS shorts = 40960 B) during loop;
  //          combine area (4 iquads * 4096 f32 = 65536 B) at end.
  __shared__ alignas(16) unsigned char smemb[65536];
  __shared__ float l_lds[128];
  unsigned short* const vlds = (unsigned short*)smemb;
  float* const comb = (float*)smemb;

  const int id = blockIdx.x;
  const int b = id & 7, i0 = (id >> 3) << 7;   // XCD-pinned batch, 128-i tile
  const int t = threadIdx.x;
  const int w = t >> 6, lane = t & 63, h = lane >> 5, l = lane & 31;
  const int jsub = w & 1, iquad = w >> 1;

  const unsigned short* kg = kbf + ((size_t)b << 16);
  const unsigned short* vg = vbf + ((size_t)b << 19);

  // Q B-frag (n=i, k=d), held in regs all kernel
  const v8s qf = *(const v8s*)(qbf + (((size_t)(b * 4096 + i0 + iquad * 32 + l)) << 4) + 8 * h);

  v16f zc;
#pragma unroll
  for (int r = 0; r < 16; ++r) zc[r] = 0.f;
  v16f acc[4];
#pragma unroll
  for (int ct = 0; ct < 4; ++ct)
#pragma unroll
    for (int r = 0; r < 16; ++r) acc[ct][r] = 0.f;
  float ls = 0.f;

  // V staging geometry (full 64-lane index): wave w stages rows [w*64, +64)
  const int vrow = w * 64 + (lane >> 1);
  const int sh16 = (lane & 1) * 8;

  if (t < 128) l_lds[t] = 0.f;

  for (int tile = 0; tile < 64; ++tile) {
    // global loads into regs: V rows for staging + this wave's K A-frag
    v8s s0 = *(const v8s*)(vg + (size_t)tile * 8192 + vrow * 16 + sh16);
    v8s s1 = *(const v8s*)(vg + (size_t)tile * 8192 + (vrow + 32) * 16 + sh16);
    v8s kf = *(const v8s*)(kg + (((size_t)(tile * 64 + jsub * 32 + l)) << 4) + 8 * h);

    __syncthreads();   // previous PV done reading vlds

    *(v8s*)(vlds + vrow * VS + sh16) = s0;
    *(v8s*)(vlds + (vrow + 32) * VS + sh16) = s1;

    // QK while staging writes drain: S^T patch (rows j, cols i)
    v16f st = __builtin_amdgcn_mfma_f32_32x32x16_bf16(kf, qf, zc, 0, 0, 0);
    float pe[16];
#pragma unroll
    for (int r = 0; r < 16; ++r) { pe[r] = __builtin_amdgcn_exp2f(st[r]); ls += pe[r]; }
    unsigned G[8];
#pragma unroll
    for (int g = 0; g < 4; ++g) {
      G[2 * g]     = pack_trunc(pe[4 * g + 1], pe[4 * g]);
      G[2 * g + 1] = pack_trunc(pe[4 * g + 3], pe[4 * g + 2]);
    }
    // half-wave exchange (proven R5/R7 mapping): 4 permutes
    unsigned S0 = h ? G[0] : G[2], S1 = h ? G[1] : G[3];
    unsigned S2 = h ? G[4] : G[6], S3 = h ? G[5] : G[7];
    unsigned R0 = (unsigned)__shfl_xor((int)S0, 32, 64);
    unsigned R1 = (unsigned)__shfl_xor((int)S1, 32, 64);
    unsigned R2 = (unsigned)__shfl_xor((int)S2, 32, 64);
    unsigned R3 = (unsigned)__shfl_xor((int)S3, 32, 64);
    v8s pf0 = h ? mk8(R0, R1, G[2], G[3]) : mk8(G[0], G[1], R0, R1);
    v8s pf1 = h ? mk8(R2, R3, G[6], G[7]) : mk8(G[4], G[5], R2, R3);

    __syncthreads();   // V staged

    // PV: all 4 ct, 2 ksteps of this wave's 32 j; acc final for this jsub
#pragma unroll
    for (int ct = 0; ct < 4; ++ct) {
      v8s vf0 = *(const v8s*)(vlds + ((jsub * 2) * 128 + ct * 32 + l) * VS + 8 * h);
      v8s vf1 = *(const v8s*)(vlds + ((jsub * 2 + 1) * 128 + ct * 32 + l) * VS + 8 * h);
      acc[ct] = __builtin_amdgcn_mfma_f32_32x32x16_bf16(vf0, pf0, acc[ct], 0, 0, 0);
      acc[ct] = __builtin_amdgcn_mfma_f32_32x32x16_bf16(vf1, pf1, acc[ct], 0, 0, 0);
    }
  }

  // l partials (both jsub waves + both h halves per i)
  atomicAdd(&l_lds[iquad * 32 + l], ls);
  __syncthreads();   // last PV done with vlds; l complete

  // combine jsub pairs via LDS overlay: jsub=1 writes, jsub=0 adds
  float* const myreg = comb + iquad * 4096;   // [ct][lane][r] f32
  if (jsub == 1) {
#pragma unroll
    for (int ct = 0; ct < 4; ++ct)
#pragma unroll
      for (int q = 0; q < 4; ++q) {
        float4 v4 = {acc[ct][4 * q], acc[ct][4 * q + 1],
                     acc[ct][4 * q + 2], acc[ct][4 * q + 3]};
        *(float4*)&myreg[ct * 1024 + lane * 16 + 4 * q] = v4;
      }
  }
  __syncthreads();
  if (jsub == 0) {
    const float li = 1.f / l_lds[iquad * 32 + l];
#pragma unroll
    for (int ct = 0; ct < 4; ++ct) {
#pragma unroll
      for (int q = 0; q < 4; ++q) {
        float4 v4 = *(float4*)&myreg[ct * 1024 + lane * 16 + 4 * q];
        acc[ct][4 * q]     += v4.x;
        acc[ct][4 * q + 1] += v4.y;
        acc[ct][4 * q + 2] += v4.z;
        acc[ct][4 * q + 3] += v4.w;
      }
#pragma unroll
      for (int r = 0; r < 16; ++r) {
        int c = ct * 32 + 4 * h + (r & 3) + 8 * (r >> 2);
        abf[((size_t)(b * 128 + c) << 12) + i0 + iquad * 32 + l] =
            f2bf_rne(acc[ct][r] * li);
      }
    }
  }
}

// ---------------------------------------------------------------------------
// proj as MFMA GEMM + bias + residual. Block 512 thr (8 waves), n-tile 64:
// nsub = w&1, ot = w>>1. All 64 abf loads hoisted up front. XCD-pinned grid.
// ---------------------------------------------------------------------------
__global__ __launch_bounds__(512)
void proj_kernel(const unsigned short* __restrict__ abf, const unsigned short* __restrict__ pwb,
                 const float* __restrict__ pb, const float* __restrict__ x,
                 float* __restrict__ out) {
  __shared__ float pbs[128];
  const int id = blockIdx.x;
  const int b = id & 7, nb = (id >> 3) << 6;   // XCD-pinned batch
  const int t = threadIdx.x;
  const int w = t >> 6, lane = t & 63, h = lane >> 5, l = lane & 31;
  const int nsub = w & 1, ot = w >> 1;
  if (t < 128) pbs[t] = pb[t];
  __syncthreads();

  const int n = nb + nsub * 32 + l;
  const unsigned short* ab = abf + (((size_t)b * 128) << 12);

  // hoist all 64 abf loads
  unsigned short av[64];
#pragma unroll
  for (int ks = 0; ks < 8; ++ks)
#pragma unroll
    for (int p = 0; p < 8; ++p)
      av[ks * 8 + p] = ab[((size_t)(ks * 16 + 8 * h + p) << 12) + n];

  v16f acc;
#pragma unroll
  for (int r = 0; r < 16; ++r) acc[r] = 0.f;

#pragma unroll
  for (int ks = 0; ks < 8; ++ks) {
    unsigned fd[4];
#pragma unroll
    for (int p = 0; p < 4; ++p)
      fd[p] = (unsigned)av[ks * 8 + 2 * p] | ((unsigned)av[ks * 8 + 2 * p + 1] << 16);
    v8s bf = mk8(fd[0], fd[1], fd[2], fd[3]);
    v8s af = *(const v8s*)(pwb + (ot * 32 + l) * 128 + ks * 16 + 8 * h);
    acc = __builtin_amdgcn_mfma_f32_32x32x16_bf16(af, bf, acc, 0, 0, 0);
  }

#pragma unroll
  for (int r = 0; r < 16; ++r) {
    int e = ot * 32 + 4 * h + (r & 3) + 8 * (r >> 2);
    size_t idx = ((size_t)(b * 128 + e) << 12) + n;
    out[idx] = acc[r] + pbs[e] + x[idx];
  }
}

// ---------------------------------------------------------------------------
extern "C" void kernel_launch(void* const* d_in, const int* in_sizes, int n_in,
                              void* d_out, int out_size, void* d_ws, size_t ws_size,
                              hipStream_t stream) {
  const float* x   = (const float*)d_in[0];
  const float* gnw = (const float*)d_in[1];
  const float* gnb = (const float*)d_in[2];
  const float* qw  = (const float*)d_in[3];
  const float* qb  = (const float*)d_in[4];
  const float* kw  = (const float*)d_in[5];
  const float* kb  = (const float*)d_in[6];
  const float* vw  = (const float*)d_in[7];
  const float* vb  = (const float*)d_in[8];
  const float* pw  = (const float*)d_in[9];
  const float* pb  = (const float*)d_in[10];
  float* out = (float*)d_out;
  char* ws = (char*)d_ws;

  float* mu_rs = (float*)(ws + WSB_MURS);
  unsigned short* wcatb = (unsigned short*)(ws + WSB_WCATB);
  float* bcat = (float*)(ws + WSB_BCAT);
  unsigned short* pwb = (unsigned short*)(ws + WSB_PWB);
  unsigned short* qbf = (unsigned short*)(ws + WSB_QBF);
  unsigned short* kbf = (unsigned short*)(ws + WSB_KBF);
  unsigned short* vbf = (unsigned short*)(ws + WSB_VBF);
  unsigned short* abf = (unsigned short*)(ws + WSB_ABF);

  hipLaunchKernelGGL(prep_kernel, dim3(145), dim3(256), 0, stream,
                     qw, qb, kw, kb, vw, vb, pw, wcatb, bcat, pwb);
  hipLaunchKernelGGL(gn_stats_kernel, dim3(256), dim3(512), 0, stream, x, mu_rs);
  hipLaunchKernelGGL(qkv_kernel, dim3(512), dim3(512), 0, stream,
                     x, gnw, gnb, mu_rs, wcatb, bcat, qbf, kbf, vbf);
  hipLaunchKernelGGL(attn_kernel, dim3(256), dim3(512), 0, stream,
                     qbf, kbf, vbf, abf);
  hipLaunchKernelGGL(proj_kernel, dim3(512), dim3(512), 0, stream,
                     abf, pwb, pb, x, out);
}

// Round 12
// 166.842 us; speedup vs baseline: 1.8210x; 1.0249x over previous
//
#include <hip/hip_runtime.h>
#include <math.h>

// B=8, C=128, N=4096, d=16, groups=32
// R12 attn: LDS-staged V (double-buffered, VS=24 conflict-free pad),
//   register-resident P, K direct global, Q from transposed [B,16,N] layout.
//   Block = 256 thr (4 waves) = (batch b, 64-i tile), grid 512, XCD-pinned.
//   2 blocks/CU co-resident (49.4 KB LDS) -> barrier drains overlap via TLP.
//   Wave = (jsub = w&1, ihalf = w>>1). Per 64-j tile (1 barrier):
//     prefetch next V tile (4x b128/thread) -> regs
//     QK (K b128 direct global) -> exp2 -> P regs -> half-wave exchange
//     PV from cur buffer (8 b128 reads, 8 MFMAs) -> acc[4]
//     write prefetched V to nxt buffer; __syncthreads()
//   Epilogue: l via LDS atomics; jsub=1 writes acc to f32 overlay (stride-36
//   rows, conflict-free), jsub=0 adds + normalizes + stores.
// R11 post-mortem: 1 blk/CU made the 2 barriers/tile serialize the LDS pipe
//   (~2500 cyc/tile vs ~1000 issue work). This buys TLP + halves barriers.

typedef short v8s __attribute__((ext_vector_type(8)));   // 8 bf16 = 4 VGPRs
typedef float v16f __attribute__((ext_vector_type(16))); // 32x32 acc

__device__ __forceinline__ unsigned short f2bf_rne(float f) {
  unsigned u = __float_as_uint(f);
  u += 0x7fffu + ((u >> 16) & 1u);
  return (unsigned short)(u >> 16);
}

__device__ __forceinline__ v8s mk8(unsigned a, unsigned b, unsigned c, unsigned d) {
  union { unsigned u[4]; v8s s; } x;
  x.u[0] = a; x.u[1] = b; x.u[2] = c; x.u[3] = d;
  return x.s;
}

// pack two fp32 -> dword of 2 bf16 (truncation) in ONE v_perm_b32
__device__ __forceinline__ unsigned pack_trunc(float hi, float lo) {
  return __builtin_amdgcn_perm(__float_as_uint(hi), __float_as_uint(lo), 0x07060302u);
}

// tiled V element index: [b][j>>4][c][j&15]
#define VT(b, n, c) (((((size_t)(b) * 256 + ((n) >> 4)) << 7) + (c)) * 16 + ((n) & 15))

// ws byte offsets
#define WSB_MURS   0u
#define WSB_WCATB  4096u       // 160*128 bf16 = 40960
#define WSB_BCAT   49152u      // 160 f32
#define WSB_PWB    65536u      // 128*128 bf16 = 32768
#define WSB_QBF    131072u     // Q^T [B,16,N] bf16 = 1 MB
#define WSB_KBF    1310720u    // K [B,N,16] bf16 = 1 MB
#define WSB_VBF    2621440u    // 8 MB (tiled)
#define WSB_ABF    11534336u   // 8 MB

// ---------------------------------------------------------------------------
__global__ void prep_kernel(const float* __restrict__ qw, const float* __restrict__ qb,
                            const float* __restrict__ kw, const float* __restrict__ kb,
                            const float* __restrict__ vw, const float* __restrict__ vb,
                            const float* __restrict__ pw,
                            unsigned short* __restrict__ wcatb, float* __restrict__ bcat,
                            unsigned short* __restrict__ pwb) {
  const float qs = 0.36067376022224085f;  // 0.25 * log2(e)
  int idx = blockIdx.x * 256 + threadIdx.x;
  if (idx < 160 * 128) {
    int o = idx >> 7, c = idx & 127;
    float val;
    if (o < 16)       val = qw[o * 128 + c] * qs;
    else if (o < 32)  val = kw[(o - 16) * 128 + c];
    else              val = vw[(o - 32) * 128 + c];
    wcatb[idx] = f2bf_rne(val);
  } else if (idx < 160 * 128 + 160) {
    int o = idx - 160 * 128;
    bcat[o] = (o < 16) ? qb[o] * qs : (o < 32) ? kb[o - 16] : vb[o - 32];
  } else if (idx < 160 * 128 + 160 + 128 * 128) {
    int j = idx - (160 * 128 + 160);
    pwb[j] = f2bf_rne(pw[j]);
  }
}

// ---------------------------------------------------------------------------
__global__ __launch_bounds__(512)
void gn_stats_kernel(const float* __restrict__ x, float* __restrict__ mu_rs) {
  const int id = blockIdx.x;              // XCD swizzle: batch = id & 7
  const int bg = (id & 7) * 32 + (id >> 3);
  const float4* xp = (const float4*)(x + (size_t)bg * 16384);
  float s = 0.f, ss = 0.f;
#pragma unroll
  for (int u = 0; u < 8; ++u) {
    int i = threadIdx.x + u * 512;
    float4 v = xp[i];
    s  += v.x + v.y + v.z + v.w;
    ss += v.x * v.x + v.y * v.y + v.z * v.z + v.w * v.w;
  }
  for (int off = 32; off > 0; off >>= 1) {
    s  += __shfl_down(s, off, 64);
    ss += __shfl_down(ss, off, 64);
  }
  __shared__ float red[16];
  int lane = threadIdx.x & 63, wid = threadIdx.x >> 6;
  if (lane == 0) { red[wid * 2] = s; red[wid * 2 + 1] = ss; }
  __syncthreads();
  if (threadIdx.x == 0) {
    float S = 0.f, SS = 0.f;
    for (int w = 0; w < 8; ++w) { S += red[w * 2]; SS += red[w * 2 + 1]; }
    float mu  = S * (1.0f / 16384.0f);
    float var = SS * (1.0f / 16384.0f) - mu * mu;
    float rs  = rsqrtf(var + 1e-5f);
    mu_rs[bg * 2]     = mu;
    mu_rs[bg * 2 + 1] = rs;
  }
}

// ---------------------------------------------------------------------------
// QKV as MFMA GEMM, GN fused. Block 512 thr (8 waves), n-tile 64.
// All 64 x-loads hoisted up front. Q stored TRANSPOSED [B,16,N] (coalesced
// stores; attn reads it once). K/V layouts unchanged. XCD-pinned grid.
// ---------------------------------------------------------------------------
__global__ __launch_bounds__(512)
void qkv_kernel(const float* __restrict__ x, const float* __restrict__ gnw,
                const float* __restrict__ gnb, const float* __restrict__ mu_rs,
                const unsigned short* __restrict__ wcatb, const float* __restrict__ bcat,
                unsigned short* __restrict__ qTb, unsigned short* __restrict__ kbf,
                unsigned short* __restrict__ vbf) {
  __shared__ float scs[128], shs[128], bsh[160];
  const int id = blockIdx.x;
  const int b = id & 7, nb = (id >> 3) << 6;   // XCD-pinned batch
  const int t = threadIdx.x;
  const int w = t >> 6, lane = t & 63, h = lane >> 5, l = lane & 31;
  const int nsub = w & 1, og = w >> 1;
  if (t < 128) {
    float mu = mu_rs[(b * 32 + (t >> 2)) * 2];
    float rs = mu_rs[(b * 32 + (t >> 2)) * 2 + 1];
    float gw = gnw[t], gb = gnb[t];
    scs[t] = rs * gw; shs[t] = gb - mu * rs * gw;
  }
  if (t < 160) bsh[t] = bcat[t];
  __syncthreads();

  const int n = nb + nsub * 32 + l;
  const float* xb = x + ((size_t)b * 128 << 12);
  const int otbase = (og == 0) ? 0 : og + 1; // ot index of acc[0]

  // hoist all 64 x loads (8 ks-steps x 8 channels) for max MLP
  float xv[64];
#pragma unroll
  for (int ks = 0; ks < 8; ++ks)
#pragma unroll
    for (int p = 0; p < 8; ++p)
      xv[ks * 8 + p] = xb[((size_t)(ks * 16 + 8 * h + p) << 12) + n];

  v16f acc[2];
#pragma unroll
  for (int a2 = 0; a2 < 2; ++a2)
#pragma unroll
    for (int r = 0; r < 16; ++r) acc[a2][r] = 0.f;

#pragma unroll
  for (int ks = 0; ks < 8; ++ks) {
    const int c0 = ks * 16 + 8 * h;
    unsigned fd[4];
#pragma unroll
    for (int p = 0; p < 4; ++p) {
      int ca = c0 + 2 * p;
      float h0 = xv[ks * 8 + 2 * p]     * scs[ca]     + shs[ca];
      float h1 = xv[ks * 8 + 2 * p + 1] * scs[ca + 1] + shs[ca + 1];
      fd[p] = (unsigned)f2bf_rne(h0) | ((unsigned)f2bf_rne(h1) << 16);
    }
    v8s bf = mk8(fd[0], fd[1], fd[2], fd[3]);
    {
      v8s af = *(const v8s*)(wcatb + (otbase * 32 + l) * 128 + ks * 16 + 8 * h);
      acc[0] = __builtin_amdgcn_mfma_f32_32x32x16_bf16(af, bf, acc[0], 0, 0, 0);
    }
    if (og == 0) {
      v8s af = *(const v8s*)(wcatb + (32 + l) * 128 + ks * 16 + 8 * h);
      acc[1] = __builtin_amdgcn_mfma_f32_32x32x16_bf16(af, bf, acc[1], 0, 0, 0);
    }
  }

  // epilogue
  if (og == 0) {
    const size_t nqk = ((size_t)b * 4096 + n) << 4;
#pragma unroll
    for (int r = 0; r < 16; ++r) {
      int o = 4 * h + (r & 3) + 8 * (r >> 2);
      unsigned short bv = f2bf_rne(acc[0][r] + bsh[o]);
      if (o < 16) qTb[((size_t)(b * 16 + o) << 12) + n] = bv;   // coalesced
      else        kbf[nqk + o - 16] = bv;
    }
#pragma unroll
    for (int r = 0; r < 16; ++r) {
      int o = 32 + 4 * h + (r & 3) + 8 * (r >> 2);
      vbf[VT(b, n, o - 32)] = f2bf_rne(acc[1][r] + bsh[o]);
    }
  } else {
#pragma unroll
    for (int r = 0; r < 16; ++r) {
      int o = otbase * 32 + 4 * h + (r & 3) + 8 * (r >> 2);
      vbf[VT(b, n, o - 32)] = f2bf_rne(acc[0][r] + bsh[o]);
    }
  }
}

// ---------------------------------------------------------------------------
// R12 flash attention. 256 thr (4 waves) per block, grid 512, 2 blocks/CU.
// Double-buffered V staging (VS=24 pad), 1 barrier/tile.
// ---------------------------------------------------------------------------
#define VS 24                     // shorts per V row (16 data + 8 pad)

__global__ __launch_bounds__(256)
void attn_kernel(const unsigned short* __restrict__ qTb,
                 const unsigned short* __restrict__ kbf,
                 const unsigned short* __restrict__ vbf,
                 unsigned short* __restrict__ abf) {
  __shared__ alignas(16) unsigned short smem[2][512 * VS];   // 49152 B
  __shared__ float l_lds[64];

  const int id = blockIdx.x;
  const int b = id & 7, i0 = (id >> 3) << 6;   // XCD-pinned batch, 64-i tile
  const int t = threadIdx.x;
  const int w = t >> 6, lane = t & 63, h = lane >> 5, l = lane & 31;
  const int jsub = w & 1, ihalf = w >> 1;

  const unsigned short* kg = kbf + ((size_t)b << 16);
  const unsigned short* vg = vbf + ((size_t)b << 19);

  // Q B-frag from Q^T [B,16,N]: 8 coalesced b16 loads, once per kernel
  const int iglob = i0 + ihalf * 32 + l;
  unsigned qd[4];
#pragma unroll
  for (int e = 0; e < 4; ++e) {
    unsigned lo = qTb[((size_t)(b * 16 + 8 * h + 2 * e) << 12) + iglob];
    unsigned hi = qTb[((size_t)(b * 16 + 8 * h + 2 * e + 1) << 12) + iglob];
    qd[e] = lo | (hi << 16);
  }
  const v8s qf = mk8(qd[0], qd[1], qd[2], qd[3]);

  v16f zc;
#pragma unroll
  for (int r = 0; r < 16; ++r) zc[r] = 0.f;
  v16f acc[4];
#pragma unroll
  for (int ct = 0; ct < 4; ++ct)
#pragma unroll
    for (int r = 0; r < 16; ++r) acc[ct][r] = 0.f;
  float ls = 0.f;

  // staging: per thread 4 chunks: rows w*128 + (lane>>1) + {0,32,64,96}
  const int srow = w * 128 + (lane >> 1);
  const int sh16 = (lane & 1) * 8;

  // prologue: stage tile 0 into buf 0
#pragma unroll
  for (int u = 0; u < 4; ++u) {
    v8s a = *(const v8s*)(vg + (size_t)(srow + 32 * u) * 16 + sh16);
    *(v8s*)(&smem[0][(srow + 32 * u) * VS + sh16]) = a;
  }
  if (t < 64) l_lds[t] = 0.f;
  __syncthreads();

  for (int tile = 0; tile < 64; ++tile) {
    const int tn = (tile + 1) & 63;   // wrap: harmless reload on last iter
    unsigned short* const cur = smem[tile & 1];
    unsigned short* const nxt = smem[(tile + 1) & 1];

    // prefetch next V tile into regs (coalesced 2KB per wave-instr)
    v8s s[4];
#pragma unroll
    for (int u = 0; u < 4; ++u)
      s[u] = *(const v8s*)(vg + (size_t)tn * 8192 + (size_t)(srow + 32 * u) * 16 + sh16);

    // K A-frag direct from global (coalesced 1KB)
    v8s kf = *(const v8s*)(kg + (((size_t)(tile * 64 + jsub * 32 + l)) << 4) + 8 * h);

    // QK: S^T patch (rows j, cols i) -> P in regs
    v16f st = __builtin_amdgcn_mfma_f32_32x32x16_bf16(kf, qf, zc, 0, 0, 0);
    float pe[16];
#pragma unroll
    for (int r = 0; r < 16; ++r) { pe[r] = __builtin_amdgcn_exp2f(st[r]); ls += pe[r]; }
    unsigned G[8];
#pragma unroll
    for (int g = 0; g < 4; ++g) {
      G[2 * g]     = pack_trunc(pe[4 * g + 1], pe[4 * g]);
      G[2 * g + 1] = pack_trunc(pe[4 * g + 3], pe[4 * g + 2]);
    }
    // half-wave exchange (proven mapping): 4 shfl + selects
    unsigned S0 = h ? G[0] : G[2], S1 = h ? G[1] : G[3];
    unsigned S2 = h ? G[4] : G[6], S3 = h ? G[5] : G[7];
    unsigned R0 = (unsigned)__shfl_xor((int)S0, 32, 64);
    unsigned R1 = (unsigned)__shfl_xor((int)S1, 32, 64);
    unsigned R2 = (unsigned)__shfl_xor((int)S2, 32, 64);
    unsigned R3 = (unsigned)__shfl_xor((int)S3, 32, 64);
    v8s pf0 = h ? mk8(R0, R1, G[2], G[3]) : mk8(G[0], G[1], R0, R1);
    v8s pf1 = h ? mk8(R2, R3, G[6], G[7]) : mk8(G[4], G[5], R2, R3);

    // PV from cur (conflict-free b128 reads)
#pragma unroll
    for (int ct = 0; ct < 4; ++ct) {
      v8s vf0 = *(const v8s*)(&cur[((jsub * 2) * 128 + ct * 32 + l) * VS + 8 * h]);
      v8s vf1 = *(const v8s*)(&cur[((jsub * 2 + 1) * 128 + ct * 32 + l) * VS + 8 * h]);
      acc[ct] = __builtin_amdgcn_mfma_f32_32x32x16_bf16(vf0, pf0, acc[ct], 0, 0, 0);
      acc[ct] = __builtin_amdgcn_mfma_f32_32x32x16_bf16(vf1, pf1, acc[ct], 0, 0, 0);
    }

    // commit prefetched tile to nxt (no reader until after barrier)
#pragma unroll
    for (int u = 0; u < 4; ++u)
      *(v8s*)(&nxt[(srow + 32 * u) * VS + sh16]) = s[u];

    __syncthreads();
  }

  // ---- epilogue ----
  atomicAdd(&l_lds[ihalf * 32 + l], ls);
  __syncthreads();   // all PV reads done; V buffers dead; l complete

  // combine jsub pairs via f32 overlay: [ct*2+ihalf][i=l][c_local], stride 36
  float* const ov = (float*)smem;   // 9212 f32 used = 36848 B < 49152
  if (jsub == 1) {
#pragma unroll
    for (int ct = 0; ct < 4; ++ct)
#pragma unroll
      for (int q = 0; q < 4; ++q) {
        float4 v4 = {acc[ct][4 * q], acc[ct][4 * q + 1],
                     acc[ct][4 * q + 2], acc[ct][4 * q + 3]};
        *(float4*)&ov[((ct * 2 + ihalf) * 32 + l) * 36 + 4 * h + 8 * q] = v4;
      }
  }
  __syncthreads();
  if (jsub == 0) {
    const float li = 1.f / l_lds[ihalf * 32 + l];
#pragma unroll
    for (int ct = 0; ct < 4; ++ct) {
#pragma unroll
      for (int q = 0; q < 4; ++q) {
        float4 v4 = *(float4*)&ov[((ct * 2 + ihalf) * 32 + l) * 36 + 4 * h + 8 * q];
        acc[ct][4 * q]     += v4.x;
        acc[ct][4 * q + 1] += v4.y;
        acc[ct][4 * q + 2] += v4.z;
        acc[ct][4 * q + 3] += v4.w;
      }
#pragma unroll
      for (int r = 0; r < 16; ++r) {
        int c = ct * 32 + 4 * h + (r & 3) + 8 * (r >> 2);
        abf[((size_t)(b * 128 + c) << 12) + (size_t)(i0 + ihalf * 32 + l)] =
            f2bf_rne(acc[ct][r] * li);
      }
    }
  }
}

// ---------------------------------------------------------------------------
// proj as MFMA GEMM + bias + residual. Block 512 thr (8 waves), n-tile 64:
// nsub = w&1, ot = w>>1. All 64 abf loads hoisted up front. XCD-pinned grid.
// ---------------------------------------------------------------------------
__global__ __launch_bounds__(512)
void proj_kernel(const unsigned short* __restrict__ abf, const unsigned short* __restrict__ pwb,
                 const float* __restrict__ pb, const float* __restrict__ x,
                 float* __restrict__ out) {
  __shared__ float pbs[128];
  const int id = blockIdx.x;
  const int b = id & 7, nb = (id >> 3) << 6;   // XCD-pinned batch
  const int t = threadIdx.x;
  const int w = t >> 6, lane = t & 63, h = lane >> 5, l = lane & 31;
  const int nsub = w & 1, ot = w >> 1;
  if (t < 128) pbs[t] = pb[t];
  __syncthreads();

  const int n = nb + nsub * 32 + l;
  const unsigned short* ab = abf + (((size_t)b * 128) << 12);

  // hoist all 64 abf loads
  unsigned short av[64];
#pragma unroll
  for (int ks = 0; ks < 8; ++ks)
#pragma unroll
    for (int p = 0; p < 8; ++p)
      av[ks * 8 + p] = ab[((size_t)(ks * 16 + 8 * h + p) << 12) + n];

  v16f acc;
#pragma unroll
  for (int r = 0; r < 16; ++r) acc[r] = 0.f;

#pragma unroll
  for (int ks = 0; ks < 8; ++ks) {
    unsigned fd[4];
#pragma unroll
    for (int p = 0; p < 4; ++p)
      fd[p] = (unsigned)av[ks * 8 + 2 * p] | ((unsigned)av[ks * 8 + 2 * p + 1] << 16);
    v8s bf = mk8(fd[0], fd[1], fd[2], fd[3]);
    v8s af = *(const v8s*)(pwb + (ot * 32 + l) * 128 + ks * 16 + 8 * h);
    acc = __builtin_amdgcn_mfma_f32_32x32x16_bf16(af, bf, acc, 0, 0, 0);
  }

#pragma unroll
  for (int r = 0; r < 16; ++r) {
    int e = ot * 32 + 4 * h + (r & 3) + 8 * (r >> 2);
    size_t idx = ((size_t)(b * 128 + e) << 12) + n;
    out[idx] = acc[r] + pbs[e] + x[idx];
  }
}

// ---------------------------------------------------------------------------
extern "C" void kernel_launch(void* const* d_in, const int* in_sizes, int n_in,
                              void* d_out, int out_size, void* d_ws, size_t ws_size,
                              hipStream_t stream) {
  const float* x   = (const float*)d_in[0];
  const float* gnw = (const float*)d_in[1];
  const float* gnb = (const float*)d_in[2];
  const float* qw  = (const float*)d_in[3];
  const float* qb  = (const float*)d_in[4];
  const float* kw  = (const float*)d_in[5];
  const float* kb  = (const float*)d_in[6];
  const float* vw  = (const float*)d_in[7];
  const float* vb  = (const float*)d_in[8];
  const float* pw  = (const float*)d_in[9];
  const float* pb  = (const float*)d_in[10];
  float* out = (float*)d_out;
  char* ws = (char*)d_ws;

  float* mu_rs = (float*)(ws + WSB_MURS);
  unsigned short* wcatb = (unsigned short*)(ws + WSB_WCATB);
  float* bcat = (float*)(ws + WSB_BCAT);
  unsigned short* pwb = (unsigned short*)(ws + WSB_PWB);
  unsigned short* qTb = (unsigned short*)(ws + WSB_QBF);
  unsigned short* kbf = (unsigned short*)(ws + WSB_KBF);
  unsigned short* vbf = (unsigned short*)(ws + WSB_VBF);
  unsigned short* abf = (unsigned short*)(ws + WSB_ABF);

  hipLaunchKernelGGL(prep_kernel, dim3(145), dim3(256), 0, stream,
                     qw, qb, kw, kb, vw, vb, pw, wcatb, bcat, pwb);
  hipLaunchKernelGGL(gn_stats_kernel, dim3(256), dim3(512), 0, stream, x, mu_rs);
  hipLaunchKernelGGL(qkv_kernel, dim3(512), dim3(512), 0, stream,
                     x, gnw, gnb, mu_rs, wcatb, bcat, qTb, kbf, vbf);
  hipLaunchKernelGGL(attn_kernel, dim3(512), dim3(256), 0, stream,
                     qTb, kbf, vbf, abf);
  hipLaunchKernelGGL(proj_kernel, dim3(512), dim3(512), 0, stream,
                     abf, pwb, pb, x, out);
}